// Round 13
// baseline (333.055 us; speedup 1.0000x reference)
//
#include <hip/hip_runtime.h>

#define N_NODES 20000
#define DEG 6
#define E_EDGES 120000
#define EPS_BN 1e-5f
#define NBLK 2500
#define EB 48      // edges per tile
#define NB 8       // nodes per tile

// ws float offsets
#define WS_S0SUM 0          // 80
#define WS_S0SQ  80         // 80
#define WS_BIAS1 160        // 128
#define WS_SC1M  288        // 128
#define WS_SH1M  416        // 128
#define WS_FSUM  544        // 128
#define WS_FSQ   672        // 128
#define WS_G0    800        // 80*80 Gram of h0 (fp32)
#define WS_STATS_FLOATS 7200
// bf16 weight tables (written by k0_fold each launch)
#define WS_WT1   7200       // 128 cols x 96 k (bf16) = 6144 floats
#define WS_WGT   13344      // 128 cols x 128 k (bf16) = 8192 floats -> end 21536

typedef float f32x4 __attribute__((ext_vector_type(4)));
typedef short bf16x8 __attribute__((ext_vector_type(8)));

__device__ __forceinline__ unsigned short f2bf(float f) {
  unsigned u = __float_as_uint(f);
  u += 0x7fffu + ((u >> 16) & 1u);   // RNE
  return (unsigned short)(u >> 16);
}
__device__ __forceinline__ unsigned pack2bf(float a, float b) {
  return (unsigned)f2bf(a) | ((unsigned)f2bf(b) << 16);
}

// ---------------------------------------------------------------- K1: bn0 stats
__global__ __launch_bounds__(256) void k1_bn0_stats(
    const float* __restrict__ node_attr, const float* __restrict__ edge_attr,
    float* __restrict__ ws) {
  __shared__ float red[256];
  const int t = threadIdx.x;
  const int b = blockIdx.x;
  if (b < 128) {  // node cols (per-node stats == per-edge stats, exact 6x repeat)
    const int c = t & 63, rl = t >> 6;
    float s = 0.f, q = 0.f;
    for (int row = b * 4 + rl; row < N_NODES; row += 512) {
      float v = node_attr[row * 64 + c];
      s += v; q += v * v;
    }
    red[t] = s;
    __syncthreads();
    if (t < 64) atomicAdd(&ws[WS_S0SUM + t], red[t] + red[t + 64] + red[t + 128] + red[t + 192]);
    __syncthreads();
    red[t] = q;
    __syncthreads();
    if (t < 64) atomicAdd(&ws[WS_S0SQ + t], red[t] + red[t + 64] + red[t + 128] + red[t + 192]);
  } else {  // edge cols
    const int c = t & 15, rl = t >> 4;
    float s = 0.f, q = 0.f;
    for (int row = (b - 128) * 16 + rl; row < E_EDGES; row += 2048) {
      float v = edge_attr[row * 16 + c];
      s += v; q += v * v;
    }
    red[t] = s;
    __syncthreads();
    if (t < 16) {
      float tot = 0.f;
      #pragma unroll
      for (int k = 0; k < 16; ++k) tot += red[t + 16 * k];
      atomicAdd(&ws[WS_S0SUM + 64 + t], tot);
    }
    __syncthreads();
    red[t] = q;
    __syncthreads();
    if (t < 16) {
      float tot = 0.f;
      #pragma unroll
      for (int k = 0; k < 16; ++k) tot += red[t + 16 * k];
      atomicAdd(&ws[WS_S0SQ + 64 + t], tot);
    }
  }
}

// -------- KGram: G0 = sum_e h0[e] h0[e]^T via graph structure (fp32, exact)
//   block 0..127 : node-node block = 6 * node^T node
//   block 128..191: node-edge cross = sum_n node[n] * (sum of its 6 edges)^T
//   block 192..255: edge-edge block = edge^T edge
__global__ __launch_bounds__(256) void kGram(
    const float* __restrict__ node_attr, const float* __restrict__ edge_attr,
    float* __restrict__ ws) {
  const int t = threadIdx.x;
  const int b = blockIdx.x;
  float* G0 = ws + WS_G0;
  if (b < 128) {
    __shared__ float rows[4][64];
    const int i = t >> 2, jb = (t & 3) * 16;
    f32x4 acc[4] = {};
    for (int r4 = b * 4; r4 < N_NODES; r4 += 512) {
      __syncthreads();
      { int rr = t >> 6, cc = t & 63;
        rows[rr][cc] = node_attr[(size_t)(r4 + rr) * 64 + cc]; }  // r4+rr <= 19999 always
      __syncthreads();
      #pragma unroll
      for (int kk = 0; kk < 4; ++kk) {
        float a = rows[kk][i];
        #pragma unroll
        for (int q = 0; q < 4; ++q) {
          f32x4 v = *(f32x4*)&rows[kk][jb + q * 4];
          acc[q][0] += a * v[0]; acc[q][1] += a * v[1];
          acc[q][2] += a * v[2]; acc[q][3] += a * v[3];
        }
      }
    }
    #pragma unroll
    for (int q = 0; q < 4; ++q)
      #pragma unroll
      for (int e = 0; e < 4; ++e)
        atomicAdd(&G0[i * 80 + jb + q * 4 + e], 6.f * acc[q][e]);
  } else if (b < 192) {
    __shared__ float nrow[4][64];
    __shared__ float es[4][16];
    const int i = t >> 2, jb = (t & 3) * 4;
    f32x4 acc = {};
    for (int n4 = (b - 128) * 4; n4 < N_NODES; n4 += 256) {
      __syncthreads();
      { int rr = t >> 6, cc = t & 63;
        nrow[rr][cc] = node_attr[(size_t)(n4 + rr) * 64 + cc]; }
      if (t < 64) {
        int rr = t >> 4, j = t & 15;
        float s = 0.f;
        #pragma unroll
        for (int kk = 0; kk < 6; ++kk)
          s += edge_attr[(size_t)((n4 + rr) * 6 + kk) * 16 + j];
        es[rr][j] = s;
      }
      __syncthreads();
      #pragma unroll
      for (int kk = 0; kk < 4; ++kk) {
        float a = nrow[kk][i];
        f32x4 v = *(f32x4*)&es[kk][jb];
        acc[0] += a * v[0]; acc[1] += a * v[1];
        acc[2] += a * v[2]; acc[3] += a * v[3];
      }
    }
    #pragma unroll
    for (int e = 0; e < 4; ++e) {
      atomicAdd(&G0[i * 80 + 64 + jb + e], acc[e]);
      atomicAdd(&G0[(64 + jb + e) * 80 + i], acc[e]);
    }
  } else {
    __shared__ float er[64][16];
    const int i = t >> 4, j = t & 15;
    float acc = 0.f;
    for (int e64 = (b - 192) * 64; e64 < E_EDGES; e64 += 64 * 64) {
      __syncthreads();
      *(float4*)&er[t >> 2][(t & 3) * 4] =
          *(const float4*)&edge_attr[(size_t)e64 * 16 + t * 4];
      __syncthreads();
      #pragma unroll
      for (int kk = 0; kk < 64; ++kk) acc += er[kk][i] * er[kk][j];
    }
    atomicAdd(&G0[(64 + i) * 80 + 64 + j], acc);
  }
}

// ------------- K0 (after k1): fold bn0 into W1 -> wt1 bf16; bias1; wgt bf16
__global__ __launch_bounds__(256) void k0_fold(
    const float* __restrict__ W1, const float* __restrict__ Wg,
    const float* __restrict__ bn0_g, const float* __restrict__ bn0_b,
    float* __restrict__ ws) {
  short* wt1 = (short*)(ws + WS_WT1);
  short* wgt = (short*)(ws + WS_WGT);
  const int t0 = blockIdx.x * 256 + threadIdx.x;
  for (int i = t0; i < 128 * 96; i += 32 * 256) {
    int n = i / 96, k = i % 96;
    float v = 0.f;
    if (k < 80) {
      float cnt = (k < 64) ? (float)N_NODES : (float)E_EDGES;
      float mu = ws[WS_S0SUM + k] / cnt;
      float var = ws[WS_S0SQ + k] / cnt - mu * mu;
      v = W1[k * 128 + n] * (bn0_g[k] * rsqrtf(var + EPS_BN));
    }
    wt1[i] = (short)f2bf(v);
  }
  for (int i = t0; i < 128 * 128; i += 32 * 256) {
    int n = i >> 7, k = i & 127;
    wgt[i] = (short)f2bf(Wg[k * 128 + n]);
  }
  if (blockIdx.x == 0 && threadIdx.x < 128) {
    int n = threadIdx.x;
    float s = 0.f;
    for (int k = 0; k < 80; ++k) {
      float cnt = (k < 64) ? (float)N_NODES : (float)E_EDGES;
      float mu = ws[WS_S0SUM + k] / cnt;
      float var = ws[WS_S0SQ + k] / cnt - mu * mu;
      float sc = bn0_g[k] * rsqrtf(var + EPS_BN);
      s += (bn0_b[k] - mu * sc) * W1[k * 128 + n];
    }
    ws[WS_BIAS1 + n] = s;
  }
}

// -------- KFin: bn1 stats analytically from G0 -> merged affine (sc1m, sh1m)
//   Sum h1   = a_c.m + E*b_c ;  Sum h1^2 = a_c^T G0 a_c + 2 b_c (a_c.m) + E b_c^2
__global__ __launch_bounds__(128) void kFin(
    const float* __restrict__ W1, const float* __restrict__ bn0_g,
    const float* __restrict__ bn1_g, const float* __restrict__ bn1_b,
    float* __restrict__ ws) {
  __shared__ float G[80][84];     // padded stride vs bank conflicts
  __shared__ float sL[80];
  __shared__ float aL[16][84];
  const int t = threadIdx.x;
  if (t < 80) {
    float cnt = (t < 64) ? (float)N_NODES : (float)E_EDGES;
    float mu = ws[WS_S0SUM + t] / cnt;
    float var = ws[WS_S0SQ + t] / cnt - mu * mu;
    sL[t] = bn0_g[t] * rsqrtf(var + EPS_BN);
  }
  for (int i = t; i < 6400; i += 128) G[i / 80][i % 80] = ws[WS_G0 + i];
  __syncthreads();
  const int ci = t >> 3, sl = t & 7;     // 16 cols/block, 8 k-slices
  const int c = blockIdx.x * 16 + ci;
  for (int k = sl; k < 80; k += 8) aL[ci][k] = sL[k] * W1[k * 128 + c];
  __syncthreads();
  float part = 0.f;
  for (int k = sl; k < 80; k += 8) {
    float dot = 0.f;
    #pragma unroll 8
    for (int l = 0; l < 80; ++l) dot += G[k][l] * aL[ci][l];
    part += aL[ci][k] * dot;
  }
  part += __shfl_xor(part, 1);
  part += __shfl_xor(part, 2);
  part += __shfl_xor(part, 4);
  if (sl == 0) {
    float am = 0.f;
    for (int k = 0; k < 80; ++k) am += aL[ci][k] * ws[WS_S0SUM + k];
    float bc = ws[WS_BIAS1 + c];
    const float invE = 1.f / (float)E_EDGES;
    float sum1 = am + (float)E_EDGES * bc;
    float sumsq = part + 2.f * bc * am + (float)E_EDGES * bc * bc;
    float mu = sum1 * invE;
    float var = sumsq * invE - mu * mu;
    float sc1 = bn1_g[c] * rsqrtf(var + EPS_BN);
    float sh1 = bn1_b[c] - mu * sc1;
    ws[WS_SC1M + c] = sc1;
    ws[WS_SH1M + c] = bc * sc1 + sh1;
  }
}

// ---- staging: raw inputs -> bf16 LDS (coalesced float4); EB=48, NB=8
#define STAGE_INPUTS()                                                         \
  if (t < NB * 16) {                                                           \
    int row = t >> 4, c4 = (t & 15) << 2;                                      \
    float4 v = *(const float4*)&node_attr[(size_t)(g * NB + row) * 64 + c4];   \
    *(uint2*)&n0s[row * 72 + c4] = make_uint2(pack2bf(v.x, v.y), pack2bf(v.z, v.w)); \
  }                                                                            \
  if (t < EB * 4) {                                                            \
    int row = t >> 2, c4 = (t & 3) << 2;                                       \
    float4 v = *(const float4*)&edge_attr[(size_t)(g * EB + row) * 16 + c4];   \
    *(uint2*)&e0s[row * 24 + c4] = make_uint2(pack2bf(v.x, v.y), pack2bf(v.z, v.w)); \
  }                                                                            \
  if (t < 8) zpad[t] = 0;

// ---- GEMM1 core: acc1[3][2] over K=96 (nodes k0..63, edges 64..79, zeros 80..95)
#define GEMM1_CORE(acc1)                                                       \
  _Pragma("unroll")                                                            \
  for (int ks = 0; ks < 3; ++ks) {                                             \
    bf16x8 bb0 = *(const bf16x8*)&wt1[(Nb + lm) * 96 + ks * 32 + lq * 8];      \
    bf16x8 bb1 = *(const bf16x8*)&wt1[(Nb + 16 + lm) * 96 + ks * 32 + lq * 8]; \
    _Pragma("unroll")                                                          \
    for (int mt = 0; mt < 3; ++mt) {                                           \
      const short* ap;                                                         \
      if (ks < 2) ap = &n0s[rowdiv6[mt] * 72 + ks * 32 + lq * 8];              \
      else ap = (lq < 2) ? &e0s[(mt * 16 + lm) * 24 + lq * 8] : zpad;          \
      bf16x8 a = *(const bf16x8*)ap;                                           \
      acc1[mt][0] = __builtin_amdgcn_mfma_f32_16x16x32_bf16(a, bb0, acc1[mt][0], 0, 0, 0); \
      acc1[mt][1] = __builtin_amdgcn_mfma_f32_16x16x32_bf16(a, bb1, acc1[mt][1], 0, 0, 0); \
    }                                                                          \
  }

// ---- K3: 48-edge tile: GEMM1+relu -> GEMM2 -> 6x6 attention -> pool -> out
__global__ __launch_bounds__(256, 6) void k3_fused(
    const float* __restrict__ node_attr, const float* __restrict__ edge_attr,
    const float* __restrict__ att_src, const float* __restrict__ att_dst,
    const float* __restrict__ gat_bias,
    float* __restrict__ out, float* __restrict__ ws) {
  __shared__ __align__(16) short n0s[NB * 72];
  __shared__ __align__(16) short e0s[EB * 24];
  __shared__ __align__(16) short zpad[8];
  __shared__ __align__(16) short h1s[EB * 136];
  __shared__ float asP[4][EB], adP[4][EB];
  __shared__ float asS[EB], adS[EB], wSm[EB];
  __shared__ float h3L[NB * 128];

  const int t = threadIdx.x;
  const int g = blockIdx.x;
  const int l = t & 63, wid = t >> 6;
  const int lm = l & 15, lq = l >> 4;
  const int Nb = wid * 32;
  const short* wt1 = (const short*)(ws + WS_WT1);
  const short* wgt = (const short*)(ws + WS_WGT);
  int rowdiv6[3];
  #pragma unroll
  for (int mt = 0; mt < 3; ++mt) rowdiv6[mt] = (mt * 16 + lm) / 6;
  float sc1c[2], sh1c[2], atS[2], atD[2];
  #pragma unroll
  for (int nt = 0; nt < 2; ++nt) {
    int col = Nb + nt * 16 + lm;
    sc1c[nt] = ws[WS_SC1M + col];
    sh1c[nt] = ws[WS_SH1M + col];
    atS[nt] = att_src[col];
    atD[nt] = att_dst[col];
  }
  *(f32x4*)&h3L[t * 4] = (f32x4){0.f, 0.f, 0.f, 0.f};
  STAGE_INPUTS();
  __syncthreads();                                    // S1
  {
    f32x4 acc1[3][2] = {};
    GEMM1_CORE(acc1);
    #pragma unroll
    for (int mt = 0; mt < 3; ++mt)
      #pragma unroll
      for (int nt = 0; nt < 2; ++nt)
        #pragma unroll
        for (int r = 0; r < 4; ++r) {
          int row = mt * 16 + lq * 4 + r;
          int col = Nb + nt * 16 + lm;
          float v = fmaxf(acc1[mt][nt][r] * sc1c[nt] + sh1c[nt], 0.f);
          h1s[row * 136 + col] = (short)f2bf(v);
        }
  }
  __syncthreads();                                    // S2
  f32x4 acc2[3][2] = {};
  #pragma unroll
  for (int ks = 0; ks < 4; ++ks) {
    bf16x8 bb0 = *(const bf16x8*)&wgt[(Nb + lm) * 128 + ks * 32 + lq * 8];
    bf16x8 bb1 = *(const bf16x8*)&wgt[(Nb + 16 + lm) * 128 + ks * 32 + lq * 8];
    #pragma unroll
    for (int mt = 0; mt < 3; ++mt) {
      bf16x8 a = *(const bf16x8*)&h1s[(mt * 16 + lm) * 136 + ks * 32 + lq * 8];
      acc2[mt][0] = __builtin_amdgcn_mfma_f32_16x16x32_bf16(a, bb0, acc2[mt][0], 0, 0, 0);
      acc2[mt][1] = __builtin_amdgcn_mfma_f32_16x16x32_bf16(a, bb1, acc2[mt][1], 0, 0, 0);
    }
  }
  #pragma unroll
  for (int mt = 0; mt < 3; ++mt)
    #pragma unroll
    for (int r = 0; r < 4; ++r) {
      float ps = acc2[mt][0][r] * atS[0] + acc2[mt][1][r] * atS[1];
      float pd = acc2[mt][0][r] * atD[0] + acc2[mt][1][r] * atD[1];
      #pragma unroll
      for (int off = 1; off < 16; off <<= 1) {
        ps += __shfl_xor(ps, off);
        pd += __shfl_xor(pd, off);
      }
      if (lm == 0) {
        int row = mt * 16 + lq * 4 + r;
        asP[wid][row] = ps;
        adP[wid][row] = pd;
      }
    }
  __syncthreads();                                    // S3
  if (t < EB) {
    asS[t] = asP[0][t] + asP[1][t] + asP[2][t] + asP[3][t];
    adS[t] = adP[0][t] + adP[1][t] + adP[2][t] + adP[3][t];
    int n = t / 6, i = t % 6, nb6 = n * 6;
    float w = 0.f;
    #pragma unroll
    for (int j = 0; j < 6; ++j) {
      float ad = adS[nb6 + j];
      float e[6], m = -1e30f;
      #pragma unroll
      for (int s = 0; s < 6; ++s) {
        float x = asS[nb6 + s] + ad;
        x = (x > 0.f) ? x : 0.2f * x;
        e[s] = x; m = fmaxf(m, x);
      }
      float den = 0.f;
      #pragma unroll
      for (int s = 0; s < 6; ++s) den += __expf(e[s] - m);
      w += __expf(e[i] - m) / (den + 1e-16f);
    }
    wSm[t] = w;
  }
  __syncthreads();                                    // S4
  #pragma unroll
  for (int mt = 0; mt < 3; ++mt)
    #pragma unroll
    for (int r = 0; r < 4; ++r) {
      int row = mt * 16 + lq * 4 + r;
      float w = wSm[row];
      int nl = row / 6;
      #pragma unroll
      for (int nt = 0; nt < 2; ++nt)
        atomicAdd(&h3L[nl * 128 + Nb + nt * 16 + lm], w * acc2[mt][nt][r]);
    }
  __syncthreads();                                    // S5
  {
    int nslot = t >> 5, c4 = (t & 31) << 2;
    f32x4 v = *(f32x4*)&h3L[nslot * 128 + c4];
    const f32x4 gb = *(const f32x4*)&gat_bias[c4];
    v[0] += 6.f * gb[0]; v[1] += 6.f * gb[1];
    v[2] += 6.f * gb[2]; v[3] += 6.f * gb[3];
    *(f32x4*)&out[(size_t)(g * NB + nslot) * 128 + c4] = v;
  }
}

// -------- K4a: bnf column stats over out (streaming)
__global__ __launch_bounds__(256) void k4a_stats(
    const float* __restrict__ out, float* __restrict__ ws) {
  __shared__ float red[8][128];
  const int t = threadIdx.x;
  const int c4 = (t & 31) << 2, rl = t >> 5;
  float fs[4] = {0.f, 0.f, 0.f, 0.f}, fq[4] = {0.f, 0.f, 0.f, 0.f};
  for (int r = blockIdx.x * 8 + rl; r < N_NODES; r += 128 * 8) {
    float4 v = *(const float4*)&out[(size_t)r * 128 + c4];
    fs[0] += v.x; fq[0] += v.x * v.x;
    fs[1] += v.y; fq[1] += v.y * v.y;
    fs[2] += v.z; fq[2] += v.z * v.z;
    fs[3] += v.w; fq[3] += v.w * v.w;
  }
  #pragma unroll
  for (int j = 0; j < 4; ++j) red[rl][c4 + j] = fs[j];
  __syncthreads();
  if (t < 128) {
    float s = 0.f;
    #pragma unroll
    for (int k = 0; k < 8; ++k) s += red[k][t];
    atomicAdd(&ws[WS_FSUM + t], s);
  }
  __syncthreads();
  #pragma unroll
  for (int j = 0; j < 4; ++j) red[rl][c4 + j] = fq[j];
  __syncthreads();
  if (t < 128) {
    float s = 0.f;
    #pragma unroll
    for (int k = 0; k < 8; ++k) s += red[k][t];
    atomicAdd(&ws[WS_FSQ + t], s);
  }
}

// -------- K4b: apply final BN in-place
__global__ __launch_bounds__(256) void k4b_apply(
    float* __restrict__ out, const float* __restrict__ ws,
    const float* __restrict__ bnf_g, const float* __restrict__ bnf_b) {
  int idx4 = blockIdx.x * 256 + threadIdx.x;
  if (idx4 >= N_NODES * 128 / 4) return;
  int c0 = (idx4 & 31) << 2;
  float4 v = ((float4*)out)[idx4];
  float4 fsv = *(const float4*)&ws[WS_FSUM + c0];
  float4 fqv = *(const float4*)&ws[WS_FSQ + c0];
  float4 g4 = *(const float4*)&bnf_g[c0];
  float4 b4 = *(const float4*)&bnf_b[c0];
  const float invN = 1.f / (float)N_NODES;
  float mu, var, sc;
  mu = fsv.x * invN; var = fqv.x * invN - mu * mu; sc = g4.x * rsqrtf(var + EPS_BN);
  v.x = (v.x - mu) * sc + b4.x;
  mu = fsv.y * invN; var = fqv.y * invN - mu * mu; sc = g4.y * rsqrtf(var + EPS_BN);
  v.y = (v.y - mu) * sc + b4.y;
  mu = fsv.z * invN; var = fqv.z * invN - mu * mu; sc = g4.z * rsqrtf(var + EPS_BN);
  v.z = (v.z - mu) * sc + b4.z;
  mu = fsv.w * invN; var = fqv.w * invN - mu * mu; sc = g4.w * rsqrtf(var + EPS_BN);
  v.w = (v.w - mu) * sc + b4.w;
  ((float4*)out)[idx4] = v;
}

extern "C" void kernel_launch(void* const* d_in, const int* in_sizes, int n_in,
                              void* d_out, int out_size, void* d_ws, size_t ws_size,
                              hipStream_t stream) {
  const float* edge_attr = (const float*)d_in[0];
  const float* node_attr = (const float*)d_in[1];
  const float* bn0_g = (const float*)d_in[2];
  const float* bn0_b = (const float*)d_in[3];
  const float* W1    = (const float*)d_in[4];
  const float* bn1_g = (const float*)d_in[5];
  const float* bn1_b = (const float*)d_in[6];
  const float* Wg    = (const float*)d_in[7];
  const float* att_src = (const float*)d_in[8];
  const float* att_dst = (const float*)d_in[9];
  const float* gat_bias = (const float*)d_in[10];
  const float* bnf_g = (const float*)d_in[11];
  const float* bnf_b = (const float*)d_in[12];
  float* ws = (float*)d_ws;
  float* out = (float*)d_out;

  hipMemsetAsync(d_ws, 0, WS_STATS_FLOATS * sizeof(float), stream);
  k1_bn0_stats<<<256, 256, 0, stream>>>(node_attr, edge_attr, ws);
  kGram<<<256, 256, 0, stream>>>(node_attr, edge_attr, ws);
  k0_fold<<<32, 256, 0, stream>>>(W1, Wg, bn0_g, bn0_b, ws);
  kFin<<<8, 128, 0, stream>>>(W1, bn0_g, bn1_g, bn1_b, ws);
  k3_fused<<<NBLK, 256, 0, stream>>>(node_attr, edge_attr, att_src, att_dst,
                                     gat_bias, out, ws);
  k4a_stats<<<128, 256, 0, stream>>>(out, ws);
  k4b_apply<<<2500, 256, 0, stream>>>(out, ws, bnf_g, bnf_b);
}